// Round 4
// baseline (849.118 us; speedup 1.0000x reference)
//
#include <hip/hip_runtime.h>
#include <hip/hip_bf16.h>

typedef __bf16 bf16_t;
typedef bf16_t bf16x8 __attribute__((ext_vector_type(8)));
typedef float  f32x4  __attribute__((ext_vector_type(4)));

#define S_LEN  2048
#define DMODEL 2048
#define NH     16
#define DH     128
#define BATCH  2
#define MROWS  (BATCH * S_LEN)   // 4096

#define NEG_BIG (-1.0e30f)

__device__ __forceinline__ bf16x8 cvt8_f32_bf16(const float* __restrict__ p) {
  float4 f0 = *(const float4*)(p);
  float4 f1 = *(const float4*)(p + 4);
  bf16x8 r;
  r[0] = (bf16_t)f0.x; r[1] = (bf16_t)f0.y; r[2] = (bf16_t)f0.z; r[3] = (bf16_t)f0.w;
  r[4] = (bf16_t)f1.x; r[5] = (bf16_t)f1.y; r[6] = (bf16_t)f1.z; r[7] = (bf16_t)f1.w;
  return r;
}

// async global(16B/lane) -> LDS. Dest = wave-uniform base + lane*16 (m97/m104).
__device__ __forceinline__ void gld16(const void* g, void* l) {
  __builtin_amdgcn_global_load_lds(
      (const __attribute__((address_space(1))) void*)g,
      (__attribute__((address_space(3))) void*)l, 16, 0, 0);
}

// ---------------- fp32 -> bf16 conversion ----------------
__global__ __launch_bounds__(256)
void cvt_bf16(const float* __restrict__ s, bf16_t* __restrict__ d, int n8) {
  int i = blockIdx.x * 256 + threadIdx.x;
  if (i < n8) *(bf16x8*)(&d[(size_t)i * 8]) = cvt8_f32_bf16(&s[(size_t)i * 8]);
}

// ---------------- GEMM: C = (A @ W^T + bias) * oscale ----------------
// A [M,K] (float: VGPR-cvt staging; bf16: global_load_lds), W [N,K] same rule.
// BK=32, unpadded LDS (m97 structure).
// mode 0: C[row*N + col]
// mode 1: ((b*NH+h)*S + s)*DH + d     (split heads, Q/K)
// mode 2: ((b*NH+h)*DH + d)*S + s     (split heads transposed, V)
template <typename TA, typename TW, typename TC>
__global__ __launch_bounds__(256)
void gemm_bt(const TA* __restrict__ A, const TW* __restrict__ W,
             const float* __restrict__ bias, TC* __restrict__ C,
             int mode, float oscale)
{
  constexpr int K = DMODEL, N = DMODEL;
  __shared__ __align__(16) bf16_t As[128 * 32];   // unpadded (global_load_lds rule)
  __shared__ __align__(16) bf16_t Bs[128 * 32];
  const int tid  = threadIdx.x;
  const int wave = tid >> 6, lane = tid & 63;
  const int quad = lane >> 4, l16 = lane & 15;
  const int bm = blockIdx.x * 128, bn = blockIdx.y * 128;
  const int wm = (wave >> 1) * 64, wn = (wave & 1) * 64;

  f32x4 acc[4][4] = {};

  for (int k0 = 0; k0 < K; k0 += 32) {
    __syncthreads();   // all waves done reading previous tile
    // ---- A tile ----
    if constexpr (__is_same(TA, float)) {
#pragma unroll
      for (int i = 0; i < 2; ++i) {
        int c = tid + i * 256, row = c >> 2, col = (c & 3) << 3;
        *(bf16x8*)(&As[row * 32 + col]) =
            cvt8_f32_bf16(&A[(size_t)(bm + row) * K + k0 + col]);
      }
    } else {
#pragma unroll
      for (int t = 0; t < 2; ++t) {
        int chunk = wave * 128 + t * 64 + lane;       // 16B chunk id, 512 total
        int row = chunk >> 2, col = (chunk & 3) << 3;
        gld16(&A[(size_t)(bm + row) * K + k0 + col], &As[row * 32 + col]);
      }
    }
    // ---- W tile ----
    if constexpr (__is_same(TW, float)) {
#pragma unroll
      for (int i = 0; i < 2; ++i) {
        int c = tid + i * 256, row = c >> 2, col = (c & 3) << 3;
        *(bf16x8*)(&Bs[row * 32 + col]) =
            cvt8_f32_bf16(&W[(size_t)(bn + row) * K + k0 + col]);
      }
    } else {
#pragma unroll
      for (int t = 0; t < 2; ++t) {
        int chunk = wave * 128 + t * 64 + lane;
        int row = chunk >> 2, col = (chunk & 3) << 3;
        gld16(&W[(size_t)(bn + row) * K + k0 + col], &Bs[row * 32 + col]);
      }
    }
    __syncthreads();   // drains vmcnt (global_load_lds) + lgkmcnt
    bf16x8 af[4], bfr[4];
#pragma unroll
    for (int i = 0; i < 4; ++i) {
      af[i]  = *(const bf16x8*)(&As[(wm + i * 16 + l16) * 32 + quad * 8]);
      bfr[i] = *(const bf16x8*)(&Bs[(wn + i * 16 + l16) * 32 + quad * 8]);
    }
#pragma unroll
    for (int mi = 0; mi < 4; ++mi)
#pragma unroll
      for (int ni = 0; ni < 4; ++ni)
        acc[mi][ni] = __builtin_amdgcn_mfma_f32_16x16x32_bf16(
            af[mi], bfr[ni], acc[mi][ni], 0, 0, 0);
  }

#pragma unroll
  for (int mi = 0; mi < 4; ++mi) {
#pragma unroll
    for (int ni = 0; ni < 4; ++ni) {
      int col = bn + wn + ni * 16 + l16;
      float bval = bias[col];
#pragma unroll
      for (int r = 0; r < 4; ++r) {
        int row = bm + wm + mi * 16 + quad * 4 + r;   // C row = quad*4+r (m89/m91)
        float vv = (acc[mi][ni][r] + bval) * oscale;
        size_t idx;
        if (mode == 0) {
          idx = (size_t)row * N + col;
        } else {
          int b = row >> 11, s = row & (S_LEN - 1);
          int h = col >> 7,  d = col & (DH - 1);
          if (mode == 1) idx = (((size_t)(b * NH + h)) * S_LEN + s) * DH + d;
          else           idx = (((size_t)(b * NH + h)) * DH + d) * S_LEN + s;
        }
        C[idx] = (TC)vv;
      }
    }
  }
}

// ---------------- Flash attention ----------------
// Q (pre-scaled by 1/sqrt(DH)), K: [B*NH, S, DH]  V: [B*NH, DH, S]  O: [B, S, D]
// Block: 128 Q-rows (4 waves x 32), 64-key tiles, VGPR prefetch, online softmax.
__global__ __launch_bounds__(256)
void attn_fwd(const bf16_t* __restrict__ Q, const bf16_t* __restrict__ Kh,
              const bf16_t* __restrict__ Vt, bf16_t* __restrict__ O,
              const int* __restrict__ causal_p)
{
  __shared__ __align__(16) bf16_t Ks[64 * 136];   // [key][dh] padded
  __shared__ __align__(16) bf16_t Vs[128 * 72];   // [dh][key] padded
  __shared__ __align__(16) bf16_t Ps[4][16 * 72]; // per-wave P relayout buffer
  const int tid  = threadIdx.x;
  const int wave = tid >> 6, lane = tid & 63;
  const int quad = lane >> 4, l16 = lane & 15;
  const int id = blockIdx.x;
  const int bh = id >> 4;
  const int qx = id & 15;
  const int qb = (qx + (bh >> 1)) & 15;   // swizzle: spread causal imbalance
  const int causal = *causal_p;

  const bf16_t* Qb = Q  + ((size_t)bh * S_LEN + qb * 128) * DH;
  const bf16_t* Kb = Kh + (size_t)bh * S_LEN * DH;
  const bf16_t* Vb = Vt + (size_t)bh * DH * S_LEN;

  bf16x8 qf[2][4];   // [row-group][kk]
#pragma unroll
  for (int mi = 0; mi < 2; ++mi)
#pragma unroll
    for (int kk = 0; kk < 4; ++kk)
      qf[mi][kk] = *(const bf16x8*)(
          &Qb[(wave * 32 + mi * 16 + l16) * DH + kk * 32 + quad * 8]);

  f32x4 oacc[2][8] = {};
  float mrow[2][4], lrow[2][4];
#pragma unroll
  for (int mi = 0; mi < 2; ++mi)
#pragma unroll
    for (int r = 0; r < 4; ++r) { mrow[mi][r] = NEG_BIG; lrow[mi][r] = 0.f; }

  const int nkb = causal ? (2 * qb + 2) : (S_LEN / 64);

  float4 ka[4], va[4];   // prefetch registers (K tile 16KB, V tile 16KB)
#define LOAD_TILE(kb_)                                                          \
  {                                                                             \
    _Pragma("unroll")                                                           \
    for (int i = 0; i < 4; ++i) {                                               \
      int c = tid + i * 256;                                                    \
      ka[i] = *(const float4*)(&Kb[(size_t)((kb_) * 64 + (c >> 4)) * DH + ((c & 15) << 3)]); \
      va[i] = *(const float4*)(&Vb[(size_t)(c >> 3) * S_LEN + (kb_) * 64 + ((c & 7) << 3)]); \
    }                                                                           \
  }

  LOAD_TILE(0)
  for (int kb = 0; kb < nkb; ++kb) {
    if (kb) __syncthreads();              // all waves done reading old Ks/Vs
#pragma unroll
    for (int i = 0; i < 4; ++i) {
      int c = tid + i * 256;
      *(float4*)(&Ks[(c >> 4) * 136 + ((c & 15) << 3)]) = ka[i];
      *(float4*)(&Vs[(c >> 3) * 72 + ((c & 7) << 3)])   = va[i];
    }
    __syncthreads();                      // publish tile kb
    if (kb + 1 < nkb) LOAD_TILE(kb + 1)   // prefetch: latency hidden by compute

    // ---- scores S = Q K^T : 32x64 per wave ----
    f32x4 sc[2][4] = {};
#pragma unroll
    for (int kk = 0; kk < 4; ++kk) {
      bf16x8 kf[4];
#pragma unroll
      for (int nf = 0; nf < 4; ++nf)
        kf[nf] = *(const bf16x8*)(&Ks[(nf * 16 + l16) * 136 + kk * 32 + quad * 8]);
#pragma unroll
      for (int nf = 0; nf < 4; ++nf) {
        sc[0][nf] = __builtin_amdgcn_mfma_f32_16x16x32_bf16(qf[0][kk], kf[nf], sc[0][nf], 0, 0, 0);
        sc[1][nf] = __builtin_amdgcn_mfma_f32_16x16x32_bf16(qf[1][kk], kf[nf], sc[1][nf], 0, 0, 0);
      }
    }

    bf16x8 pf[2][2];
#pragma unroll
    for (int mi = 0; mi < 2; ++mi) {
      const int qrow0 = qb * 128 + wave * 32 + mi * 16 + quad * 4;
      const bool need_mask = causal && (kb * 64 + 63 > qb * 128 + wave * 32 + mi * 16);
      float p[4][4];  // [nf][r]
#pragma unroll
      for (int nf = 0; nf < 4; ++nf)
#pragma unroll
        for (int r = 0; r < 4; ++r) {
          float s = sc[mi][nf][r];   // 1/sqrt(DH) folded into Q projection
          if (need_mask && (kb * 64 + nf * 16 + l16 > qrow0 + r)) s = NEG_BIG;
          p[nf][r] = s;
        }
#pragma unroll
      for (int r = 0; r < 4; ++r) {
        float mx = fmaxf(fmaxf(p[0][r], p[1][r]), fmaxf(p[2][r], p[3][r]));
#pragma unroll
        for (int d = 8; d >= 1; d >>= 1) mx = fmaxf(mx, __shfl_xor(mx, d));
        float mnew  = fmaxf(mrow[mi][r], mx);
        float alpha = __expf(mrow[mi][r] - mnew);
        mrow[mi][r] = mnew;
        float rsum = 0.f;
#pragma unroll
        for (int nf = 0; nf < 4; ++nf) {
          float e = __expf(p[nf][r] - mnew);
          p[nf][r] = e;
          rsum += e;
        }
#pragma unroll
        for (int d = 8; d >= 1; d >>= 1) rsum += __shfl_xor(rsum, d);
        lrow[mi][r] = lrow[mi][r] * alpha + rsum;
#pragma unroll
        for (int nf = 0; nf < 8; ++nf) oacc[mi][nf][r] *= alpha;
      }
      // P: C-layout -> A-layout, wave-local LDS round-trip (no barrier needed)
      bf16_t* Pw = &Ps[wave][0];
#pragma unroll
      for (int r = 0; r < 4; ++r)
#pragma unroll
        for (int nf = 0; nf < 4; ++nf)
          Pw[(quad * 4 + r) * 72 + nf * 16 + l16] = (bf16_t)p[nf][r];
      asm volatile("s_waitcnt lgkmcnt(0)" ::: "memory");   // writes visible in-wave
      pf[mi][0] = *(const bf16x8*)(&Pw[l16 * 72 + quad * 8]);
      pf[mi][1] = *(const bf16x8*)(&Pw[l16 * 72 + 32 + quad * 8]);
      asm volatile("s_waitcnt lgkmcnt(0)" ::: "memory");   // reads done before reuse
    }

    // ---- O += P V (vf fragments shared across both row-groups) ----
#pragma unroll
    for (int ks = 0; ks < 2; ++ks)
#pragma unroll
      for (int nf = 0; nf < 8; ++nf) {
        bf16x8 vf = *(const bf16x8*)(&Vs[(nf * 16 + l16) * 72 + ks * 32 + quad * 8]);
        oacc[0][nf] = __builtin_amdgcn_mfma_f32_16x16x32_bf16(pf[0][ks], vf, oacc[0][nf], 0, 0, 0);
        oacc[1][nf] = __builtin_amdgcn_mfma_f32_16x16x32_bf16(pf[1][ks], vf, oacc[1][nf], 0, 0, 0);
      }
  }

  // epilogue: O[b, s, h*DH + dh] = oacc / l
  const int b = bh >> 4, h = bh & 15;
#pragma unroll
  for (int mi = 0; mi < 2; ++mi)
#pragma unroll
    for (int nf = 0; nf < 8; ++nf) {
      int dh = nf * 16 + l16;
#pragma unroll
      for (int r = 0; r < 4; ++r) {
        int s = qb * 128 + wave * 32 + mi * 16 + quad * 4 + r;
        float vv = oacc[mi][nf][r] / fmaxf(lrow[mi][r], 1e-20f);
        O[((size_t)(b * S_LEN + s)) * DMODEL + h * DH + dh] = (bf16_t)vv;
      }
    }
}

extern "C" void kernel_launch(void* const* d_in, const int* in_sizes, int n_in,
                              void* d_out, int out_size, void* d_ws, size_t ws_size,
                              hipStream_t stream) {
  const float* q  = (const float*)d_in[0];
  const float* k  = (const float*)d_in[1];
  const float* v  = (const float*)d_in[2];
  const float* Wq = (const float*)d_in[3];
  const float* bq = (const float*)d_in[4];
  const float* Wk = (const float*)d_in[5];
  const float* bk = (const float*)d_in[6];
  const float* Wv = (const float*)d_in[7];
  const float* bv = (const float*)d_in[8];
  const float* Wo = (const float*)d_in[9];
  const float* bo = (const float*)d_in[10];
  const int*   cm = (const int*)d_in[11];

  float* out = (float*)d_out;
  const size_t NA = (size_t)MROWS * DMODEL;     // 8,388,608
  const size_t NW = (size_t)DMODEL * DMODEL;    // 4,194,304
  const float qscale = 0.08838834764831845f;    // 1/sqrt(128)

  bf16_t* base = (bf16_t*)d_ws;
  const bool cw = ws_size >= (4 * NA + 4 * NW) * sizeof(bf16_t);  // ~101 MB
  bf16_t *Wqb = base, *Wkb = base + NW, *Wvb = base + 2 * NW, *Wob = base + 3 * NW;
  bf16_t* inter = cw ? (base + 4 * NW) : base;
  bf16_t *Qh = inter, *Kh = inter + NA, *Vh = inter + 2 * NA, *Ao = inter + 3 * NA;

  dim3 gg(MROWS / 128, DMODEL / 128), bb(256);
  if (cw) {
    int n8 = (int)(NW / 8);
    dim3 cg((n8 + 255) / 256);
    cvt_bf16<<<cg, bb, 0, stream>>>(Wq, Wqb, n8);
    cvt_bf16<<<cg, bb, 0, stream>>>(Wk, Wkb, n8);
    cvt_bf16<<<cg, bb, 0, stream>>>(Wv, Wvb, n8);
    cvt_bf16<<<cg, bb, 0, stream>>>(Wo, Wob, n8);
    gemm_bt<float, bf16_t, bf16_t><<<gg, bb, 0, stream>>>(q, Wqb, bq, Qh, 1, qscale);
    gemm_bt<float, bf16_t, bf16_t><<<gg, bb, 0, stream>>>(k, Wkb, bk, Kh, 1, 1.0f);
    gemm_bt<float, bf16_t, bf16_t><<<gg, bb, 0, stream>>>(v, Wvb, bv, Vh, 2, 1.0f);
  } else {
    gemm_bt<float, float, bf16_t><<<gg, bb, 0, stream>>>(q, Wq, bq, Qh, 1, qscale);
    gemm_bt<float, float, bf16_t><<<gg, bb, 0, stream>>>(k, Wk, bk, Kh, 1, 1.0f);
    gemm_bt<float, float, bf16_t><<<gg, bb, 0, stream>>>(v, Wv, bv, Vh, 2, 1.0f);
  }
  attn_fwd<<<dim3(512), bb, 0, stream>>>(Qh, Kh, Vh, Ao, cm);
  if (cw) gemm_bt<bf16_t, bf16_t, float><<<gg, bb, 0, stream>>>(Ao, Wob, bo, out, 0, 1.0f);
  else    gemm_bt<bf16_t, float,  float><<<gg, bb, 0, stream>>>(Ao, Wo,  bo, out, 0, 1.0f);
}